// Round 9
// baseline (408.572 us; speedup 1.0000x reference)
//
#include <hip/hip_runtime.h>
#include <cstddef>

// ---------------------------------------------------------------------------
// Fused equivariant decoder, MI355X (gfx950) — round 10 (resubmit; R8 broker
// timeout left it unmeasured).
// R9 post-mortem: (256,3) still spills (~31MB scratch writes, VGPR 84 of a
//   168 budget => allocator split + over-pressure). Cause theory: full unroll
//   of the unit loops lets LLVM CSE the loop-invariant weight-frag loads
//   into huge live ranges (L<=2: up to 128 VGPR of weights) -> spill; and
//   ~170KB straight-line code thrashes the 32KB I$.
// R10:
//   - unit loops ROLLED (#pragma unroll 1): ~10x smaller code, no cross-unit
//     CSE live ranges.
//   - weights explicitly hoisted to registers for L>=3 chains only (MT=2 ->
//     aw1/aw2/aw3 = 24 VGPR), covering 40/48 units; L<=2 reloads per unit.
//   - everything else unchanged ((256,3), K=16 chaining, 3 barriers).
// Weights pre-packed in d_ws.
// ---------------------------------------------------------------------------

typedef _Float16 half8 __attribute__((ext_vector_type(8)));
typedef _Float16 half4 __attribute__((ext_vector_type(4)));
typedef float    f32x4 __attribute__((ext_vector_type(4)));
typedef float    fvec4 __attribute__((ext_vector_type(4)));

#define B_ROWS   16
#define IN_DIM   3840
#define OUT_COLS 49
#define GP  264           // gate row pitch (256 used)
#define HSP 72            // scalar-hidden row pitch (64 used)

// LDS map (elements of _Float16); bases all 16B-aligned.
#define OFF_G1  0         // 16*264 = 4224
#define OFF_G2  4224
#define OFF_G3  8448
#define OFF_HS1 12672     // 16*72 = 1152
#define OFF_HS2 13824
#define SMEM_ELTS 14976   // *2B = 29952 B

#define P2BASE 106496
#define P3BASE 139264

// ---------------------------------------------------------------------------
// Weight prep.
// bi 0..7  (w1 blocks, contracted by 16x16x32): frag f=(mt*KF+kf)*64+lane
//   holds half8: W[i][o]*scale, i=kf*32+(lane>>4)*8+j (j=0..7), o=mt*16+(lane&15).
// bi 8..23 (w2/w3 blocks, contracted by 16x16x16): frag f=mt*(K/16)+ks, lane
//   holds half4: W[i][o]*scale, i=ks*16+(lane>>4)*4+j (j=0..3), o=mt*16+(lane&15),
//   stored at region + f*256 + lane*4 (halves). Region sizes = K*N either way.
// ---------------------------------------------------------------------------
__global__ __launch_bounds__(256) void prep_weights(
    const float* __restrict__ w1, const float* __restrict__ w2,
    const float* __restrict__ w3, _Float16* __restrict__ packed)
{
  static const int K_[24]    = {256,256,128,128,64,64,64,64,  64,64,64,64,32,32,32,32,
                                64,64,64,64,32,32,32,32};
  static const int N_[24]    = {64,256,64,64,32,32,32,32,  64,256,64,64,32,32,32,32,
                                64,256,64,64,32,32,32,32};
  static const int woff_[24] = {0,16384,81920,90112,98304,100352,102400,104448,
                                0,4096,20480,24576,28672,29696,30720,31744,
                                0,4096,20480,24576,28672,29696,30720,31744};
  static const int poff_[24] = {0,16384,81920,90112,98304,100352,102400,104448,
                                106496,110592,126976,131072,135168,136192,137216,138240,
                                139264,143360,159744,163840,167936,168960,169984,171008};
  const int g = blockIdx.x * 256 + threadIdx.x;   // 0 .. 21503
  int bi = 0;
#pragma unroll
  for (int i = 1; i < 24; ++i) if (g * 8 >= poff_[i]) bi = i;
  const float* w = (bi < 8) ? w1 : ((bi < 16) ? w2 : w3);
  const int rel8 = g - poff_[bi] / 8;
  const int K = K_[bi], N = N_[bi];
  const float scale = 1.0f / sqrtf((float)K);
  half8 vv;
  if (bi < 8) {
    const int lane = rel8 & 63;
    const int fi   = rel8 >> 6;
    const int KF = K >> 5;
    const int kf = fi % KF;
    const int mt = fi / KF;
    const int k0 = kf * 32 + (lane >> 4) * 8;
    const int o  = mt * 16 + (lane & 15);
#pragma unroll
    for (int j = 0; j < 8; ++j)
      vv[j] = (_Float16)(w[woff_[bi] + (size_t)(k0 + j) * N + o] * scale);
  } else {
    // 16x16x16 A-frag layout: thread covers lanes lp, lp+1 of frag f.
    const int f  = rel8 >> 5;            // 256 halves per frag, 8 per thread
    const int lp = (rel8 & 31) << 1;
    const int KF16 = K >> 4;
    const int ks = f % KF16;
    const int mt = f / KF16;
#pragma unroll
    for (int t = 0; t < 2; ++t) {
      const int l  = lp + t;
      const int i0 = ks * 16 + (l >> 4) * 4;
      const int o  = mt * 16 + (l & 15);
#pragma unroll
      for (int j = 0; j < 4; ++j)
        vv[t * 4 + j] = (_Float16)(w[woff_[bi] + (size_t)(i0 + j) * N + o] * scale);
    }
  }
  *(half8*)(packed + (size_t)g * 8) = vv;
}

// ---------------------------------------------------------------------------
// Per-chain compile-time parameters.
// ---------------------------------------------------------------------------
template<int L> struct CP {
  static constexpr int TWOL1 = 2 * L + 1;
  static constexpr int K1  = (L <= 2) ? 128 : 64;
  static constexpr int N1  = (L <= 2) ? 64  : 32;
  static constexpr int KF1 = K1 / 32;
  static constexpr int MT  = N1 / 16;          // also = K/16 of L2/L3
  static constexpr int INOFF = (L==1)?256:(L==2)?640:(L==3)?1280:(L==4)?1728:(L==5)?2304:3008;
  static constexpr int P1    = (L==1)?81920:(L==2)?90112:(L==3)?98304:(L==4)?100352:(L==5)?102400:104448;
  static constexpr int P2R   = (L==1)?20480:(L==2)?24576:(L==3)?28672:(L==4)?29696:(L==5)?30720:31744;
  static constexpr int GO    = (L==1)?0:(L==2)?64:(L==3)?128:(L==4)?160:(L==5)?192:224;
  static constexpr int W4O   = (L==1)?64:(L==2)?128:(L==3)?192:(L==4)?224:(L==5)?256:288;
  static constexpr float SCALE = (N1 == 64) ? 0.125f : 0.17677669529663687f;
};

// Direct global B-frag loads for one unit: lane (col,quad) needs
// X[c][kf*32+quad*8+j] = vraw[(b0+b)*IN_DIM + INOFF + i*TWOL1 + m].
template<int L>
__device__ __forceinline__ void unit_load(const float* __restrict__ vraw,
                                          int b0, int ct, float (&tmp)[CP<L>::KF1 * 8])
{
  using P = CP<L>;
  const int lane = threadIdx.x & 63;
  const int col  = lane & 15;
  const int quad = lane >> 4;
  const int c = ct * 16 + col;
  const int b = c / P::TWOL1;
  const int m = c - b * P::TWOL1;
  const float* base = vraw + (size_t)(b0 + b) * IN_DIM + P::INOFF + m
                    + (size_t)(quad * 8) * P::TWOL1;
#pragma unroll
  for (int kf = 0; kf < P::KF1; ++kf)
#pragma unroll
    for (int j = 0; j < 8; ++j)
      tmp[kf * 8 + j] = base[(size_t)(kf * 32 + j) * P::TWOL1];
}

// Convert a gathered float buffer into MFMA B-fragments (half8 per kf).
template<int L>
__device__ __forceinline__ void cvt_frags(const float (&tmp)[CP<L>::KF1 * 8],
                                          half8 (&bf)[CP<L>::KF1])
{
#pragma unroll
  for (int kf = 0; kf < CP<L>::KF1; ++kf)
#pragma unroll
    for (int j = 0; j < 8; ++j) bf[kf][j] = (_Float16)tmp[kf * 8 + j];
}

// Shared epilogue pieces -------------------------------------------------

// One unit with weights re-loaded from L2 each call (used for L<=2, MT=4).
template<int L>
__device__ __forceinline__ void unit_compute(
    const half8 (&bf)[CP<L>::KF1], const _Float16* __restrict__ pk,
    const _Float16* G1, const _Float16* G2, const _Float16* G3,
    const float* __restrict__ w4, float* __restrict__ out, int b0, int ct)
{
  using P = CP<L>;
  const int lane = threadIdx.x & 63;
  const int col  = lane & 15;
  const int quad = lane >> 4;
  const int c = ct * 16 + col;
  const int b = c / P::TWOL1;
  const int m = c - b * P::TWOL1;

  // ---- L1 (16x16x32) -> gated half4 per mt tile ----
  half4 ph1[P::MT];
#pragma unroll
  for (int mt = 0; mt < P::MT; ++mt) {
    f32x4 acc = {0.f, 0.f, 0.f, 0.f};
#pragma unroll
    for (int kf = 0; kf < P::KF1; ++kf) {
      const half8 av = *(const half8*)(pk + P::P1 + (size_t)((mt * P::KF1 + kf) * 64 + lane) * 8);
      acc = __builtin_amdgcn_mfma_f32_16x16x32_f16(av, bf[kf], acc, 0, 0, 0);
    }
    const int o0 = mt * 16 + quad * 4;
    const half4 g4 = *(const half4*)(G1 + b * GP + P::GO + o0);
    half4 h;
#pragma unroll
    for (int r = 0; r < 4; ++r) h[r] = (_Float16)(acc[r] * (float)g4[r]);
    ph1[mt] = h;
  }

  // ---- L2 (16x16x16): B = ph1 directly ----
  half4 ph2[P::MT];
#pragma unroll
  for (int mt = 0; mt < P::MT; ++mt) {
    f32x4 acc = {0.f, 0.f, 0.f, 0.f};
#pragma unroll
    for (int ks = 0; ks < P::MT; ++ks) {
      const half4 av = *(const half4*)(pk + P2BASE + P::P2R + (size_t)((mt * P::MT + ks) * 64 + lane) * 4);
      acc = __builtin_amdgcn_mfma_f32_16x16x16f16(av, ph1[ks], acc, 0, 0, 0);
    }
    const int o0 = mt * 16 + quad * 4;
    const half4 g4 = *(const half4*)(G2 + b * GP + P::GO + o0);
    half4 h;
#pragma unroll
    for (int r = 0; r < 4; ++r) h[r] = (_Float16)(acc[r] * (float)g4[r]);
    ph2[mt] = h;
  }

  // ---- L3 (16x16x16) + folded w4 dot ----
  float s = 0.f;
#pragma unroll
  for (int mt = 0; mt < P::MT; ++mt) {
    f32x4 acc = {0.f, 0.f, 0.f, 0.f};
#pragma unroll
    for (int ks = 0; ks < P::MT; ++ks) {
      const half4 av = *(const half4*)(pk + P3BASE + P::P2R + (size_t)((mt * P::MT + ks) * 64 + lane) * 4);
      acc = __builtin_amdgcn_mfma_f32_16x16x16f16(av, ph2[ks], acc, 0, 0, 0);
    }
    const int o0 = mt * 16 + quad * 4;
    const half4 g4 = *(const half4*)(G3 + b * GP + P::GO + o0);
#pragma unroll
    for (int r = 0; r < 4; ++r)
      s += acc[r] * (float)g4[r] * w4[P::W4O + o0 + r];
  }
  s += __shfl_xor(s, 16, 64);
  s += __shfl_xor(s, 32, 64);
  if (quad == 0)
    out[(size_t)(b0 + b) * OUT_COLS + L * L + m] = s * P::SCALE;
}

// One unit with weights held in registers (used for L>=3, MT=2).
template<int L>
__device__ __forceinline__ void unit_compute_reg(
    const half8 (&bf)[CP<L>::KF1],
    const half8 (&aw1)[CP<L>::MT * CP<L>::KF1],
    const half4 (&aw2)[CP<L>::MT * CP<L>::MT],
    const half4 (&aw3)[CP<L>::MT * CP<L>::MT],
    const _Float16* G1, const _Float16* G2, const _Float16* G3,
    const float* __restrict__ w4, float* __restrict__ out, int b0, int ct)
{
  using P = CP<L>;
  const int lane = threadIdx.x & 63;
  const int col  = lane & 15;
  const int quad = lane >> 4;
  const int c = ct * 16 + col;
  const int b = c / P::TWOL1;
  const int m = c - b * P::TWOL1;

  half4 ph1[P::MT];
#pragma unroll
  for (int mt = 0; mt < P::MT; ++mt) {
    f32x4 acc = {0.f, 0.f, 0.f, 0.f};
#pragma unroll
    for (int kf = 0; kf < P::KF1; ++kf)
      acc = __builtin_amdgcn_mfma_f32_16x16x32_f16(aw1[mt * P::KF1 + kf], bf[kf], acc, 0, 0, 0);
    const int o0 = mt * 16 + quad * 4;
    const half4 g4 = *(const half4*)(G1 + b * GP + P::GO + o0);
    half4 h;
#pragma unroll
    for (int r = 0; r < 4; ++r) h[r] = (_Float16)(acc[r] * (float)g4[r]);
    ph1[mt] = h;
  }

  half4 ph2[P::MT];
#pragma unroll
  for (int mt = 0; mt < P::MT; ++mt) {
    f32x4 acc = {0.f, 0.f, 0.f, 0.f};
#pragma unroll
    for (int ks = 0; ks < P::MT; ++ks)
      acc = __builtin_amdgcn_mfma_f32_16x16x16f16(aw2[mt * P::MT + ks], ph1[ks], acc, 0, 0, 0);
    const int o0 = mt * 16 + quad * 4;
    const half4 g4 = *(const half4*)(G2 + b * GP + P::GO + o0);
    half4 h;
#pragma unroll
    for (int r = 0; r < 4; ++r) h[r] = (_Float16)(acc[r] * (float)g4[r]);
    ph2[mt] = h;
  }

  float s = 0.f;
#pragma unroll
  for (int mt = 0; mt < P::MT; ++mt) {
    f32x4 acc = {0.f, 0.f, 0.f, 0.f};
#pragma unroll
    for (int ks = 0; ks < P::MT; ++ks)
      acc = __builtin_amdgcn_mfma_f32_16x16x16f16(aw3[mt * P::MT + ks], ph2[ks], acc, 0, 0, 0);
    const int o0 = mt * 16 + quad * 4;
    const half4 g4 = *(const half4*)(G3 + b * GP + P::GO + o0);
#pragma unroll
    for (int r = 0; r < 4; ++r)
      s += acc[r] * (float)g4[r] * w4[P::W4O + o0 + r];
  }
  s += __shfl_xor(s, 16, 64);
  s += __shfl_xor(s, 32, 64);
  if (quad == 0)
    out[(size_t)(b0 + b) * OUT_COLS + L * L + m] = s * P::SCALE;
}

// Chain runner: ROLLED unit loop (#pragma unroll 1). Single tmp buffer,
// next-unit gather issued right after cvt consumes the current one.
// L>=3: weights hoisted to registers (24 VGPR) across the loop.
template<int L, int CT0, int NCT>
__device__ __forceinline__ void run_chain(
    const float* __restrict__ vraw, const _Float16* __restrict__ pk,
    const _Float16* G1, const _Float16* G2, const _Float16* G3,
    const float* __restrict__ w4, float* __restrict__ out, int b0)
{
  using P = CP<L>;
  float tmp[P::KF1 * 8];
  unit_load<L>(vraw, b0, CT0, tmp);
  if constexpr (L >= 3) {
    const int lane = threadIdx.x & 63;
    half8 aw1[P::MT * P::KF1];
    half4 aw2[P::MT * P::MT];
    half4 aw3[P::MT * P::MT];
#pragma unroll
    for (int f = 0; f < P::MT * P::KF1; ++f)
      aw1[f] = *(const half8*)(pk + P::P1 + (size_t)(f * 64 + lane) * 8);
#pragma unroll
    for (int f = 0; f < P::MT * P::MT; ++f) {
      aw2[f] = *(const half4*)(pk + P2BASE + P::P2R + (size_t)(f * 64 + lane) * 4);
      aw3[f] = *(const half4*)(pk + P3BASE + P::P2R + (size_t)(f * 64 + lane) * 4);
    }
#pragma unroll 1
    for (int u = 0; u < NCT; ++u) {
      half8 bf[P::KF1];
      cvt_frags<L>(tmp, bf);
      if (u + 1 < NCT) unit_load<L>(vraw, b0, CT0 + u + 1, tmp);
      unit_compute_reg<L>(bf, aw1, aw2, aw3, G1, G2, G3, w4, out, b0, CT0 + u);
    }
  } else {
#pragma unroll 1
    for (int u = 0; u < NCT; ++u) {
      half8 bf[P::KF1];
      cvt_frags<L>(tmp, bf);
      if (u + 1 < NCT) unit_load<L>(vraw, b0, CT0 + u + 1, tmp);
      unit_compute<L>(bf, pk, G1, G2, G3, w4, out, b0, CT0 + u);
    }
  }
}

// ---------------------------------------------------------------------------
// Scalar (l=0) chain. B-frags: lane col = batch row b. Tiles distributed
// across waves -> handoff stays in LDS (Hs1/Hs2), read in K=16 layout.
// ---------------------------------------------------------------------------
__device__ __forceinline__ void load_scal_frags(const float* __restrict__ vraw,
                                                int b0, half8 (&sf)[8])
{
  const int lane = threadIdx.x & 63;
  const int col  = lane & 15;
  const int quad = lane >> 4;
  const float* base = vraw + (size_t)(b0 + col) * IN_DIM + quad * 8;
#pragma unroll
  for (int kf = 0; kf < 8; ++kf) {
    const fvec4 a = *(const fvec4*)(base + kf * 32);
    const fvec4 b2 = *(const fvec4*)(base + kf * 32 + 4);
#pragma unroll
    for (int j = 0; j < 4; ++j) { sf[kf][j] = (_Float16)a[j]; sf[kf][4 + j] = (_Float16)b2[j]; }
  }
}

// W0: scalar L1 (K=256, 16x16x32). silu tile = wave; gate tiles = wave*4..+3.
__device__ __forceinline__ void scal_L1(const half8 (&sf)[8],
    const _Float16* __restrict__ pk, _Float16* Hs1, _Float16* G1v)
{
  const int lane = threadIdx.x & 63;
  const int wv   = threadIdx.x >> 6;
  const int col  = lane & 15;
  const int quad = lane >> 4;
  {
    f32x4 acc = {0.f, 0.f, 0.f, 0.f};
#pragma unroll
    for (int kf = 0; kf < 8; ++kf) {
      const half8 av = *(const half8*)(pk + (size_t)((wv * 8 + kf) * 64 + lane) * 8);
      acc = __builtin_amdgcn_mfma_f32_16x16x32_f16(av, sf[kf], acc, 0, 0, 0);
    }
    const int o0 = wv * 16 + quad * 4;
    half4 h;
#pragma unroll
    for (int r = 0; r < 4; ++r) { const float z = acc[r]; h[r] = (_Float16)(z / (1.f + __expf(-z))); }
    *(half4*)(Hs1 + col * HSP + o0) = h;
  }
#pragma unroll
  for (int t = 0; t < 4; ++t) {
    const int mt = wv * 4 + t;
    f32x4 acc = {0.f, 0.f, 0.f, 0.f};
#pragma unroll
    for (int kf = 0; kf < 8; ++kf) {
      const half8 av = *(const half8*)(pk + 16384 + (size_t)((mt * 8 + kf) * 64 + lane) * 8);
      acc = __builtin_amdgcn_mfma_f32_16x16x32_f16(av, sf[kf], acc, 0, 0, 0);
    }
    const int o0 = mt * 16 + quad * 4;
    half4 g;
#pragma unroll
    for (int r = 0; r < 4; ++r) g[r] = (_Float16)(1.f / (1.f + __expf(-acc[r])));
    *(half4*)(G1v + col * GP + o0) = g;
  }
}

// W1: scalar L2 (K=64, 16x16x16). Hs read as half4 per K-step.
__device__ __forceinline__ void scal_mid(const _Float16* HsIn,
    const _Float16* __restrict__ pkS, const _Float16* __restrict__ pkG,
    _Float16* HsOut, _Float16* Gv)
{
  const int lane = threadIdx.x & 63;
  const int wv   = threadIdx.x >> 6;
  const int col  = lane & 15;
  const int quad = lane >> 4;
  half4 bf4[4];
#pragma unroll
  for (int ks = 0; ks < 4; ++ks)
    bf4[ks] = *(const half4*)(HsIn + col * HSP + ks * 16 + quad * 4);
  {
    f32x4 acc = {0.f, 0.f, 0.f, 0.f};
#pragma unroll
    for (int ks = 0; ks < 4; ++ks) {
      const half4 av = *(const half4*)(pkS + (size_t)((wv * 4 + ks) * 64 + lane) * 4);
      acc = __builtin_amdgcn_mfma_f32_16x16x16f16(av, bf4[ks], acc, 0, 0, 0);
    }
    const int o0 = wv * 16 + quad * 4;
    half4 h;
#pragma unroll
    for (int r = 0; r < 4; ++r) { const float z = acc[r]; h[r] = (_Float16)(z / (1.f + __expf(-z))); }
    *(half4*)(HsOut + col * HSP + o0) = h;
  }
#pragma unroll
  for (int t = 0; t < 4; ++t) {
    const int mt = wv * 4 + t;
    f32x4 acc = {0.f, 0.f, 0.f, 0.f};
#pragma unroll
    for (int ks = 0; ks < 4; ++ks) {
      const half4 av = *(const half4*)(pkG + (size_t)((mt * 4 + ks) * 64 + lane) * 4);
      acc = __builtin_amdgcn_mfma_f32_16x16x16f16(av, bf4[ks], acc, 0, 0, 0);
    }
    const int o0 = mt * 16 + quad * 4;
    half4 g;
#pragma unroll
    for (int r = 0; r < 4; ++r) g[r] = (_Float16)(1.f / (1.f + __expf(-acc[r])));
    *(half4*)(Gv + col * GP + o0) = g;
  }
}

// W2: scalar L3 (K=64, 16x16x16): wave0 silu tiles + folded w4 dot;
// waves 1-3 do G3.
__device__ __forceinline__ void scal_last(const _Float16* Hs2,
    const _Float16* __restrict__ pkS, const _Float16* __restrict__ pkG,
    _Float16* G3v, const float* __restrict__ w4, float* __restrict__ out, int b0)
{
  const int lane = threadIdx.x & 63;
  const int wv   = threadIdx.x >> 6;
  const int col  = lane & 15;
  const int quad = lane >> 4;
  half4 bf4[4];
#pragma unroll
  for (int ks = 0; ks < 4; ++ks)
    bf4[ks] = *(const half4*)(Hs2 + col * HSP + ks * 16 + quad * 4);
  if (wv == 0) {
    float s = 0.f;
#pragma unroll
    for (int mt = 0; mt < 4; ++mt) {
      f32x4 acc = {0.f, 0.f, 0.f, 0.f};
#pragma unroll
      for (int ks = 0; ks < 4; ++ks) {
        const half4 av = *(const half4*)(pkS + (size_t)((mt * 4 + ks) * 64 + lane) * 4);
        acc = __builtin_amdgcn_mfma_f32_16x16x16f16(av, bf4[ks], acc, 0, 0, 0);
      }
      const int o0 = mt * 16 + quad * 4;
#pragma unroll
      for (int r = 0; r < 4; ++r) {
        const float z = acc[r];
        s += (z / (1.f + __expf(-z))) * w4[o0 + r];
      }
    }
    s += __shfl_xor(s, 16, 64);
    s += __shfl_xor(s, 32, 64);
    if (quad == 0) out[(size_t)(b0 + col) * OUT_COLS] = s * 0.125f;
  } else {
    const int t0 = (wv == 1) ? 0 : (wv == 2) ? 6 : 11;
    const int tn = (wv == 1) ? 6 : 5;
    for (int t = 0; t < tn; ++t) {
      const int mt = t0 + t;
      f32x4 acc = {0.f, 0.f, 0.f, 0.f};
#pragma unroll
      for (int ks = 0; ks < 4; ++ks) {
        const half4 av = *(const half4*)(pkG + (size_t)((mt * 4 + ks) * 64 + lane) * 4);
        acc = __builtin_amdgcn_mfma_f32_16x16x16f16(av, bf4[ks], acc, 0, 0, 0);
      }
      const int o0 = mt * 16 + quad * 4;
      half4 g;
#pragma unroll
      for (int r = 0; r < 4; ++r) g[r] = (_Float16)(1.f / (1.f + __expf(-acc[r])));
      *(half4*)(G3v + col * GP + o0) = g;
    }
  }
}

// ---------------------------------------------------------------------------
// Main kernel.
// ---------------------------------------------------------------------------
__global__ __launch_bounds__(256, 3) void fused_decoder(
    const float* __restrict__ vraw, const float* __restrict__ w4,
    const _Float16* __restrict__ pk, float* __restrict__ out)
{
  __shared__ __align__(16) _Float16 smem[SMEM_ELTS];
  _Float16* G1  = smem + OFF_G1;
  _Float16* G2  = smem + OFF_G2;
  _Float16* G3  = smem + OFF_G3;
  _Float16* Hs1 = smem + OFF_HS1;
  _Float16* Hs2 = smem + OFF_HS2;
  const int wv = threadIdx.x >> 6;
  const int b0 = blockIdx.x * B_ROWS;

  half8 sf[8];
  load_scal_frags(vraw, b0, sf);
  scal_L1(sf, pk, Hs1, G1);
  __syncthreads();
  scal_mid(Hs1, pk + P2BASE, pk + P2BASE + 4096, Hs2, G2);
  __syncthreads();
  scal_last(Hs2, pk + P3BASE, pk + P3BASE + 4096, G3, w4, out, b0);
  __syncthreads();

  // phase 2: cost-balanced static wave assignment (no barriers).
  if (wv == 0) {
    run_chain<2, 0, 5>(vraw, pk, G1, G2, G3, w4, out, b0);
    run_chain<3, 0, 4>(vraw, pk, G1, G2, G3, w4, out, b0);
  } else if (wv == 1) {
    run_chain<1, 0, 3>(vraw, pk, G1, G2, G3, w4, out, b0);
    run_chain<3, 4, 3>(vraw, pk, G1, G2, G3, w4, out, b0);
    run_chain<4, 0, 5>(vraw, pk, G1, G2, G3, w4, out, b0);
  } else if (wv == 2) {
    run_chain<6, 0, 13>(vraw, pk, G1, G2, G3, w4, out, b0);
    run_chain<4, 5, 1>(vraw, pk, G1, G2, G3, w4, out, b0);
  } else {
    run_chain<5, 0, 11>(vraw, pk, G1, G2, G3, w4, out, b0);
    run_chain<4, 6, 3>(vraw, pk, G1, G2, G3, w4, out, b0);
  }
}

extern "C" void kernel_launch(void* const* d_in, const int* in_sizes, int n_in,
                              void* d_out, int out_size, void* d_ws, size_t ws_size,
                              hipStream_t stream)
{
  (void)in_sizes; (void)n_in; (void)out_size; (void)ws_size;
  const float* vraw = (const float*)d_in[0];
  const float* w1   = (const float*)d_in[1];
  const float* w2   = (const float*)d_in[2];
  const float* w3   = (const float*)d_in[3];
  const float* w4   = (const float*)d_in[4];
  float* out = (float*)d_out;
  _Float16* packed = (_Float16*)d_ws;   // 172032 elems = 344064 B

  prep_weights<<<84, 256, 0, stream>>>(w1, w2, w3, packed);
  fused_decoder<<<16384 / B_ROWS, 256, 0, stream>>>(vraw, w4, packed, out);
}

// Round 14
// 377.924 us; speedup vs baseline: 1.0811x; 1.0811x over previous
//
#include <hip/hip_runtime.h>
#include <cstddef>

// ---------------------------------------------------------------------------
// Fused equivariant decoder, MI355X (gfx950) — round 11 (5th submission;
// R10-R13 broker timeouts left it unmeasured).
// R10 post-mortem: decoder 162us INVARIANT across handoff/occupancy/register
//   changes (R4-R10); VGPR 84 unchanged; all pipes <20%. WRITE ~43MB is
//   output write-amplification, not scratch. Diagnosis: vector-memory
//   ADDRESS/SEGMENT throughput bound — ~900 scattered dword gathers/block,
//   each instruction touching ~8-16 discontiguous segments.
// R11: L>=3 chains (40/48 units, ~640 scattered instrs) load their unit
//   input as CONTIGUOUS row-blocks with coalesced dwordx4 into wave-private
//   LDS scratch (10KB/wave), then ds_read the strided fragments. T14 split:
//   issue loads(u+1) -> compute(u) -> ds_write(u+1) keeps latency hidden.
//   No fences needed (wave-private, in-order DS). L<=2 chains unchanged.
//   LDS 29.9 -> 69.3KB (2 blocks/CU; occupancy demonstrably not the
//   limiter). launch_bounds (256,2).
// Weights pre-packed in d_ws.
// ---------------------------------------------------------------------------

typedef _Float16 half8 __attribute__((ext_vector_type(8)));
typedef _Float16 half4 __attribute__((ext_vector_type(4)));
typedef float    f32x4 __attribute__((ext_vector_type(4)));
typedef float    fvec4 __attribute__((ext_vector_type(4)));

#define B_ROWS   16
#define IN_DIM   3840
#define OUT_COLS 49
#define GP  264           // gate row pitch (256 used)
#define HSP 72            // scalar-hidden / scratch row pitch (64 used)

// LDS map (elements of _Float16); bases all 16B-aligned.
#define OFF_G1  0         // 16*264 = 4224
#define OFF_G2  4224
#define OFF_G3  8448
#define OFF_HS1 12672     // 16*72 = 1152
#define OFF_HS2 13824
#define OFF_SCR 14976     // byte 29952; + wave*2560 floats (10240 B)
#define SCRW_F  2560      // floats per wave (max need 2496: L6 3-row)
#define SMEM_ELTS 35456   // 14976 + 4*2560*2 halves = 70912 B

#define P2BASE 106496
#define P3BASE 139264

// ---------------------------------------------------------------------------
// Weight prep (unchanged from R10).
// bi 0..7  (w1, 16x16x32): frag f=(mt*KF+kf)*64+lane holds half8:
//   W[i][o]*scale, i=kf*32+(lane>>4)*8+j, o=mt*16+(lane&15).
// bi 8..23 (w2/w3, 16x16x16): frag f=mt*(K/16)+ks, lane holds half4:
//   W[i][o]*scale, i=ks*16+(lane>>4)*4+j, o=mt*16+(lane&15).
// ---------------------------------------------------------------------------
__global__ __launch_bounds__(256) void prep_weights(
    const float* __restrict__ w1, const float* __restrict__ w2,
    const float* __restrict__ w3, _Float16* __restrict__ packed)
{
  static const int K_[24]    = {256,256,128,128,64,64,64,64,  64,64,64,64,32,32,32,32,
                                64,64,64,64,32,32,32,32};
  static const int N_[24]    = {64,256,64,64,32,32,32,32,  64,256,64,64,32,32,32,32,
                                64,256,64,64,32,32,32,32};
  static const int woff_[24] = {0,16384,81920,90112,98304,100352,102400,104448,
                                0,4096,20480,24576,28672,29696,30720,31744,
                                0,4096,20480,24576,28672,29696,30720,31744};
  static const int poff_[24] = {0,16384,81920,90112,98304,100352,102400,104448,
                                106496,110592,126976,131072,135168,136192,137216,138240,
                                139264,143360,159744,163840,167936,168960,169984,171008};
  const int g = blockIdx.x * 256 + threadIdx.x;   // 0 .. 21503
  int bi = 0;
#pragma unroll
  for (int i = 1; i < 24; ++i) if (g * 8 >= poff_[i]) bi = i;
  const float* w = (bi < 8) ? w1 : ((bi < 16) ? w2 : w3);
  const int rel8 = g - poff_[bi] / 8;
  const int K = K_[bi], N = N_[bi];
  const float scale = 1.0f / sqrtf((float)K);
  half8 vv;
  if (bi < 8) {
    const int lane = rel8 & 63;
    const int fi   = rel8 >> 6;
    const int KF = K >> 5;
    const int kf = fi % KF;
    const int mt = fi / KF;
    const int k0 = kf * 32 + (lane >> 4) * 8;
    const int o  = mt * 16 + (lane & 15);
#pragma unroll
    for (int j = 0; j < 8; ++j)
      vv[j] = (_Float16)(w[woff_[bi] + (size_t)(k0 + j) * N + o] * scale);
  } else {
    const int f  = rel8 >> 5;
    const int lp = (rel8 & 31) << 1;
    const int KF16 = K >> 4;
    const int ks = f % KF16;
    const int mt = f / KF16;
#pragma unroll
    for (int t = 0; t < 2; ++t) {
      const int l  = lp + t;
      const int i0 = ks * 16 + (l >> 4) * 4;
      const int o  = mt * 16 + (l & 15);
#pragma unroll
      for (int j = 0; j < 4; ++j)
        vv[t * 4 + j] = (_Float16)(w[woff_[bi] + (size_t)(i0 + j) * N + o] * scale);
    }
  }
  *(half8*)(packed + (size_t)g * 8) = vv;
}

// ---------------------------------------------------------------------------
// Per-chain compile-time parameters.
// ---------------------------------------------------------------------------
template<int L> struct CP {
  static constexpr int TWOL1 = 2 * L + 1;
  static constexpr int K1  = (L <= 2) ? 128 : 64;
  static constexpr int N1  = (L <= 2) ? 64  : 32;
  static constexpr int KF1 = K1 / 32;
  static constexpr int MT  = N1 / 16;
  static constexpr int INOFF = (L==1)?256:(L==2)?640:(L==3)?1280:(L==4)?1728:(L==5)?2304:3008;
  static constexpr int P1    = (L==1)?81920:(L==2)?90112:(L==3)?98304:(L==4)?100352:(L==5)?102400:104448;
  static constexpr int P2R   = (L==1)?20480:(L==2)?24576:(L==3)?28672:(L==4)?29696:(L==5)?30720:31744;
  static constexpr int GO    = (L==1)?0:(L==2)?64:(L==3)?128:(L==4)?160:(L==5)?192:224;
  static constexpr int W4O   = (L==1)?64:(L==2)?128:(L==3)?192:(L==4)?224:(L==5)?256:288;
  static constexpr float SCALE = (N1 == 64) ? 0.125f : 0.17677669529663687f;
};

// ---------------------------------------------------------------------------
// L<=2 path: scattered direct gather (unchanged from R10).
// ---------------------------------------------------------------------------
template<int L>
__device__ __forceinline__ void unit_load(const float* __restrict__ vraw,
                                          int b0, int ct, float (&tmp)[CP<L>::KF1 * 8])
{
  using P = CP<L>;
  const int lane = threadIdx.x & 63;
  const int col  = lane & 15;
  const int quad = lane >> 4;
  const int c = ct * 16 + col;
  const int b = c / P::TWOL1;
  const int m = c - b * P::TWOL1;
  const float* base = vraw + (size_t)(b0 + b) * IN_DIM + P::INOFF + m
                    + (size_t)(quad * 8) * P::TWOL1;
#pragma unroll
  for (int kf = 0; kf < P::KF1; ++kf)
#pragma unroll
    for (int j = 0; j < 8; ++j)
      tmp[kf * 8 + j] = base[(size_t)(kf * 32 + j) * P::TWOL1];
}

template<int L>
__device__ __forceinline__ void cvt_frags(const float (&tmp)[CP<L>::KF1 * 8],
                                          half8 (&bf)[CP<L>::KF1])
{
#pragma unroll
  for (int kf = 0; kf < CP<L>::KF1; ++kf)
#pragma unroll
    for (int j = 0; j < 8; ++j) bf[kf][j] = (_Float16)tmp[kf * 8 + j];
}

// ---------------------------------------------------------------------------
// L>=3 path: coalesced LDS staging.
// Unit ct needs rows blo..bhi (2-4) of the chain's contiguous (2L+1)*64-dword
// block. stage_issue: MAXIT coalesced dwordx4 -> regs (clamped tail reloads
// last chunk). stage_write: vmcnt + ds_write to wave-private scratch.
// read_frags: strided ds_read of the MFMA B-fragment.
// ---------------------------------------------------------------------------
template<int L> struct SG {
  static constexpr int NW   = CP<L>::TWOL1 * 64;   // dwords per row block
  static constexpr int NW4  = CP<L>::TWOL1 * 16;   // dwordx4 chunks per row
  static constexpr int MAXROWS = (L == 3) ? 4 : 3;
  static constexpr int MAXIT = (NW4 * MAXROWS + 63) / 64;
};

template<int L>
__device__ __forceinline__ void stage_issue(const float* __restrict__ vraw,
    int b0, int ct, fvec4 (&rv)[SG<L>::MAXIT])
{
  using P = CP<L>;
  const int lane = threadIdx.x & 63;
  const int blo = (ct * 16) / P::TWOL1;
  const int bhi = (ct * 16 + 15) / P::TWOL1;
  const int chunks = SG<L>::NW4 * (bhi - blo + 1);
  const float* base = vraw + (size_t)(b0 + blo) * IN_DIM + P::INOFF;
#pragma unroll
  for (int it = 0; it < SG<L>::MAXIT; ++it) {
    int t = it * 64 + lane;
    t = (t < chunks) ? t : (chunks - 1);          // clamp: redundant reload, safe
    const int r = t / SG<L>::NW4;
    const int o = t - r * SG<L>::NW4;
    rv[it] = *(const fvec4*)(base + (size_t)r * IN_DIM + o * 4);
  }
}

template<int L>
__device__ __forceinline__ void stage_write(const fvec4 (&rv)[SG<L>::MAXIT],
    float* scr, int ct)
{
  using P = CP<L>;
  const int lane = threadIdx.x & 63;
  const int blo = (ct * 16) / P::TWOL1;
  const int bhi = (ct * 16 + 15) / P::TWOL1;
  const int chunks = SG<L>::NW4 * (bhi - blo + 1);
#pragma unroll
  for (int it = 0; it < SG<L>::MAXIT; ++it) {
    int t = it * 64 + lane;
    t = (t < chunks) ? t : (chunks - 1);          // duplicate writes of same data
    const int r = t / SG<L>::NW4;
    const int o = t - r * SG<L>::NW4;
    *(fvec4*)(scr + r * SG<L>::NW + o * 4) = rv[it];
  }
}

template<int L>
__device__ __forceinline__ void read_frags(const float* scr, int ct,
                                           half8 (&bf)[CP<L>::KF1])
{
  using P = CP<L>;
  const int lane = threadIdx.x & 63;
  const int col  = lane & 15;
  const int quad = lane >> 4;
  const int c = ct * 16 + col;
  const int blo = (ct * 16) / P::TWOL1;
  const int b = c / P::TWOL1;
  const int m = c - b * P::TWOL1;
  const float* base = scr + (b - blo) * SG<L>::NW + m + quad * 8 * P::TWOL1;
#pragma unroll
  for (int kf = 0; kf < P::KF1; ++kf)
#pragma unroll
    for (int j = 0; j < 8; ++j)
      bf[kf][j] = (_Float16)base[(kf * 32 + j) * P::TWOL1];
}

// ---------------------------------------------------------------------------
// Unit computes (unchanged from R10).
// ---------------------------------------------------------------------------
template<int L>
__device__ __forceinline__ void unit_compute(
    const half8 (&bf)[CP<L>::KF1], const _Float16* __restrict__ pk,
    const _Float16* G1, const _Float16* G2, const _Float16* G3,
    const float* __restrict__ w4, float* __restrict__ out, int b0, int ct)
{
  using P = CP<L>;
  const int lane = threadIdx.x & 63;
  const int col  = lane & 15;
  const int quad = lane >> 4;
  const int c = ct * 16 + col;
  const int b = c / P::TWOL1;
  const int m = c - b * P::TWOL1;

  half4 ph1[P::MT];
#pragma unroll
  for (int mt = 0; mt < P::MT; ++mt) {
    f32x4 acc = {0.f, 0.f, 0.f, 0.f};
#pragma unroll
    for (int kf = 0; kf < P::KF1; ++kf) {
      const half8 av = *(const half8*)(pk + P::P1 + (size_t)((mt * P::KF1 + kf) * 64 + lane) * 8);
      acc = __builtin_amdgcn_mfma_f32_16x16x32_f16(av, bf[kf], acc, 0, 0, 0);
    }
    const int o0 = mt * 16 + quad * 4;
    const half4 g4 = *(const half4*)(G1 + b * GP + P::GO + o0);
    half4 h;
#pragma unroll
    for (int r = 0; r < 4; ++r) h[r] = (_Float16)(acc[r] * (float)g4[r]);
    ph1[mt] = h;
  }

  half4 ph2[P::MT];
#pragma unroll
  for (int mt = 0; mt < P::MT; ++mt) {
    f32x4 acc = {0.f, 0.f, 0.f, 0.f};
#pragma unroll
    for (int ks = 0; ks < P::MT; ++ks) {
      const half4 av = *(const half4*)(pk + P2BASE + P::P2R + (size_t)((mt * P::MT + ks) * 64 + lane) * 4);
      acc = __builtin_amdgcn_mfma_f32_16x16x16f16(av, ph1[ks], acc, 0, 0, 0);
    }
    const int o0 = mt * 16 + quad * 4;
    const half4 g4 = *(const half4*)(G2 + b * GP + P::GO + o0);
    half4 h;
#pragma unroll
    for (int r = 0; r < 4; ++r) h[r] = (_Float16)(acc[r] * (float)g4[r]);
    ph2[mt] = h;
  }

  float s = 0.f;
#pragma unroll
  for (int mt = 0; mt < P::MT; ++mt) {
    f32x4 acc = {0.f, 0.f, 0.f, 0.f};
#pragma unroll
    for (int ks = 0; ks < P::MT; ++ks) {
      const half4 av = *(const half4*)(pk + P3BASE + P::P2R + (size_t)((mt * P::MT + ks) * 64 + lane) * 4);
      acc = __builtin_amdgcn_mfma_f32_16x16x16f16(av, ph2[ks], acc, 0, 0, 0);
    }
    const int o0 = mt * 16 + quad * 4;
    const half4 g4 = *(const half4*)(G3 + b * GP + P::GO + o0);
#pragma unroll
    for (int r = 0; r < 4; ++r)
      s += acc[r] * (float)g4[r] * w4[P::W4O + o0 + r];
  }
  s += __shfl_xor(s, 16, 64);
  s += __shfl_xor(s, 32, 64);
  if (quad == 0)
    out[(size_t)(b0 + b) * OUT_COLS + L * L + m] = s * P::SCALE;
}

template<int L>
__device__ __forceinline__ void unit_compute_reg(
    const half8 (&bf)[CP<L>::KF1],
    const half8 (&aw1)[CP<L>::MT * CP<L>::KF1],
    const half4 (&aw2)[CP<L>::MT * CP<L>::MT],
    const half4 (&aw3)[CP<L>::MT * CP<L>::MT],
    const _Float16* G1, const _Float16* G2, const _Float16* G3,
    const float* __restrict__ w4, float* __restrict__ out, int b0, int ct)
{
  using P = CP<L>;
  const int lane = threadIdx.x & 63;
  const int col  = lane & 15;
  const int quad = lane >> 4;
  const int c = ct * 16 + col;
  const int b = c / P::TWOL1;
  const int m = c - b * P::TWOL1;

  half4 ph1[P::MT];
#pragma unroll
  for (int mt = 0; mt < P::MT; ++mt) {
    f32x4 acc = {0.f, 0.f, 0.f, 0.f};
#pragma unroll
    for (int kf = 0; kf < P::KF1; ++kf)
      acc = __builtin_amdgcn_mfma_f32_16x16x32_f16(aw1[mt * P::KF1 + kf], bf[kf], acc, 0, 0, 0);
    const int o0 = mt * 16 + quad * 4;
    const half4 g4 = *(const half4*)(G1 + b * GP + P::GO + o0);
    half4 h;
#pragma unroll
    for (int r = 0; r < 4; ++r) h[r] = (_Float16)(acc[r] * (float)g4[r]);
    ph1[mt] = h;
  }

  half4 ph2[P::MT];
#pragma unroll
  for (int mt = 0; mt < P::MT; ++mt) {
    f32x4 acc = {0.f, 0.f, 0.f, 0.f};
#pragma unroll
    for (int ks = 0; ks < P::MT; ++ks)
      acc = __builtin_amdgcn_mfma_f32_16x16x16f16(aw2[mt * P::MT + ks], ph1[ks], acc, 0, 0, 0);
    const int o0 = mt * 16 + quad * 4;
    const half4 g4 = *(const half4*)(G2 + b * GP + P::GO + o0);
    half4 h;
#pragma unroll
    for (int r = 0; r < 4; ++r) h[r] = (_Float16)(acc[r] * (float)g4[r]);
    ph2[mt] = h;
  }

  float s = 0.f;
#pragma unroll
  for (int mt = 0; mt < P::MT; ++mt) {
    f32x4 acc = {0.f, 0.f, 0.f, 0.f};
#pragma unroll
    for (int ks = 0; ks < P::MT; ++ks)
      acc = __builtin_amdgcn_mfma_f32_16x16x16f16(aw3[mt * P::MT + ks], ph2[ks], acc, 0, 0, 0);
    const int o0 = mt * 16 + quad * 4;
    const half4 g4 = *(const half4*)(G3 + b * GP + P::GO + o0);
#pragma unroll
    for (int r = 0; r < 4; ++r)
      s += acc[r] * (float)g4[r] * w4[P::W4O + o0 + r];
  }
  s += __shfl_xor(s, 16, 64);
  s += __shfl_xor(s, 32, 64);
  if (quad == 0)
    out[(size_t)(b0 + b) * OUT_COLS + L * L + m] = s * P::SCALE;
}

// ---------------------------------------------------------------------------
// Chain runners.
// ---------------------------------------------------------------------------
// L<=2: rolled loop, scattered gather with depth-1 reg prefetch (R10).
template<int L, int CT0, int NCT>
__device__ __forceinline__ void run_chain(
    const float* __restrict__ vraw, const _Float16* __restrict__ pk,
    const _Float16* G1, const _Float16* G2, const _Float16* G3,
    const float* __restrict__ w4, float* __restrict__ out, int b0)
{
  using P = CP<L>;
  float tmp[P::KF1 * 8];
  unit_load<L>(vraw, b0, CT0, tmp);
#pragma unroll 1
  for (int u = 0; u < NCT; ++u) {
    half8 bf[P::KF1];
    cvt_frags<L>(tmp, bf);
    if (u + 1 < NCT) unit_load<L>(vraw, b0, CT0 + u + 1, tmp);
    unit_compute<L>(bf, pk, G1, G2, G3, w4, out, b0, CT0 + u);
  }
}

// L>=3: coalesced LDS-staged, T14 split (issue early / write late), weights
// in registers. Wave-private scr, no fences (in-order DS per wave).
template<int L, int CT0, int NCT>
__device__ __forceinline__ void run_chain_staged(
    const float* __restrict__ vraw, const _Float16* __restrict__ pk,
    const _Float16* G1, const _Float16* G2, const _Float16* G3,
    const float* __restrict__ w4, float* __restrict__ out, int b0, float* scr)
{
  using P = CP<L>;
  const int lane = threadIdx.x & 63;
  half8 aw1[P::MT * P::KF1];
  half4 aw2[P::MT * P::MT];
  half4 aw3[P::MT * P::MT];
#pragma unroll
  for (int f = 0; f < P::MT * P::KF1; ++f)
    aw1[f] = *(const half8*)(pk + P::P1 + (size_t)(f * 64 + lane) * 8);
#pragma unroll
  for (int f = 0; f < P::MT * P::MT; ++f) {
    aw2[f] = *(const half4*)(pk + P2BASE + P::P2R + (size_t)(f * 64 + lane) * 4);
    aw3[f] = *(const half4*)(pk + P3BASE + P::P2R + (size_t)(f * 64 + lane) * 4);
  }

  fvec4 rv[SG<L>::MAXIT];
  stage_issue<L>(vraw, b0, CT0, rv);
  stage_write<L>(rv, scr, CT0);          // vmcnt wait here (prologue only)
#pragma unroll 1
  for (int u = 0; u < NCT; ++u) {
    half8 bf[P::KF1];
    read_frags<L>(scr, CT0 + u, bf);                 // ds_read current unit
    if (u + 1 < NCT) stage_issue<L>(vraw, b0, CT0 + u + 1, rv);  // loads in flight
    unit_compute_reg<L>(bf, aw1, aw2, aw3, G1, G2, G3, w4, out, b0, CT0 + u);
    if (u + 1 < NCT) stage_write<L>(rv, scr, CT0 + u + 1);       // after compute
  }
}

// ---------------------------------------------------------------------------
// Scalar (l=0) chain (unchanged).
// ---------------------------------------------------------------------------
__device__ __forceinline__ void load_scal_frags(const float* __restrict__ vraw,
                                                int b0, half8 (&sf)[8])
{
  const int lane = threadIdx.x & 63;
  const int col  = lane & 15;
  const int quad = lane >> 4;
  const float* base = vraw + (size_t)(b0 + col) * IN_DIM + quad * 8;
#pragma unroll
  for (int kf = 0; kf < 8; ++kf) {
    const fvec4 a = *(const fvec4*)(base + kf * 32);
    const fvec4 b2 = *(const fvec4*)(base + kf * 32 + 4);
#pragma unroll
    for (int j = 0; j < 4; ++j) { sf[kf][j] = (_Float16)a[j]; sf[kf][4 + j] = (_Float16)b2[j]; }
  }
}

__device__ __forceinline__ void scal_L1(const half8 (&sf)[8],
    const _Float16* __restrict__ pk, _Float16* Hs1, _Float16* G1v)
{
  const int lane = threadIdx.x & 63;
  const int wv   = threadIdx.x >> 6;
  const int col  = lane & 15;
  const int quad = lane >> 4;
  {
    f32x4 acc = {0.f, 0.f, 0.f, 0.f};
#pragma unroll
    for (int kf = 0; kf < 8; ++kf) {
      const half8 av = *(const half8*)(pk + (size_t)((wv * 8 + kf) * 64 + lane) * 8);
      acc = __builtin_amdgcn_mfma_f32_16x16x32_f16(av, sf[kf], acc, 0, 0, 0);
    }
    const int o0 = wv * 16 + quad * 4;
    half4 h;
#pragma unroll
    for (int r = 0; r < 4; ++r) { const float z = acc[r]; h[r] = (_Float16)(z / (1.f + __expf(-z))); }
    *(half4*)(Hs1 + col * HSP + o0) = h;
  }
#pragma unroll
  for (int t = 0; t < 4; ++t) {
    const int mt = wv * 4 + t;
    f32x4 acc = {0.f, 0.f, 0.f, 0.f};
#pragma unroll
    for (int kf = 0; kf < 8; ++kf) {
      const half8 av = *(const half8*)(pk + 16384 + (size_t)((mt * 8 + kf) * 64 + lane) * 8);
      acc = __builtin_amdgcn_mfma_f32_16x16x32_f16(av, sf[kf], acc, 0, 0, 0);
    }
    const int o0 = mt * 16 + quad * 4;
    half4 g;
#pragma unroll
    for (int r = 0; r < 4; ++r) g[r] = (_Float16)(1.f / (1.f + __expf(-acc[r])));
    *(half4*)(G1v + col * GP + o0) = g;
  }
}

__device__ __forceinline__ void scal_mid(const _Float16* HsIn,
    const _Float16* __restrict__ pkS, const _Float16* __restrict__ pkG,
    _Float16* HsOut, _Float16* Gv)
{
  const int lane = threadIdx.x & 63;
  const int wv   = threadIdx.x >> 6;
  const int col  = lane & 15;
  const int quad = lane >> 4;
  half4 bf4[4];
#pragma unroll
  for (int ks = 0; ks < 4; ++ks)
    bf4[ks] = *(const half4*)(HsIn + col * HSP + ks * 16 + quad * 4);
  {
    f32x4 acc = {0.f, 0.f, 0.f, 0.f};
#pragma unroll
    for (int ks = 0; ks < 4; ++ks) {
      const half4 av = *(const half4*)(pkS + (size_t)((wv * 4 + ks) * 64 + lane) * 4);
      acc = __builtin_amdgcn_mfma_f32_16x16x16f16(av, bf4[ks], acc, 0, 0, 0);
    }
    const int o0 = wv * 16 + quad * 4;
    half4 h;
#pragma unroll
    for (int r = 0; r < 4; ++r) { const float z = acc[r]; h[r] = (_Float16)(z / (1.f + __expf(-z))); }
    *(half4*)(HsOut + col * HSP + o0) = h;
  }
#pragma unroll
  for (int t = 0; t < 4; ++t) {
    const int mt = wv * 4 + t;
    f32x4 acc = {0.f, 0.f, 0.f, 0.f};
#pragma unroll
    for (int ks = 0; ks < 4; ++ks) {
      const half4 av = *(const half4*)(pkG + (size_t)((mt * 4 + ks) * 64 + lane) * 4);
      acc = __builtin_amdgcn_mfma_f32_16x16x16f16(av, bf4[ks], acc, 0, 0, 0);
    }
    const int o0 = mt * 16 + quad * 4;
    half4 g;
#pragma unroll
    for (int r = 0; r < 4; ++r) g[r] = (_Float16)(1.f / (1.f + __expf(-acc[r])));
    *(half4*)(Gv + col * GP + o0) = g;
  }
}

__device__ __forceinline__ void scal_last(const _Float16* Hs2,
    const _Float16* __restrict__ pkS, const _Float16* __restrict__ pkG,
    _Float16* G3v, const float* __restrict__ w4, float* __restrict__ out, int b0)
{
  const int lane = threadIdx.x & 63;
  const int wv   = threadIdx.x >> 6;
  const int col  = lane & 15;
  const int quad = lane >> 4;
  half4 bf4[4];
#pragma unroll
  for (int ks = 0; ks < 4; ++ks)
    bf4[ks] = *(const half4*)(Hs2 + col * HSP + ks * 16 + quad * 4);
  if (wv == 0) {
    float s = 0.f;
#pragma unroll
    for (int mt = 0; mt < 4; ++mt) {
      f32x4 acc = {0.f, 0.f, 0.f, 0.f};
#pragma unroll
      for (int ks = 0; ks < 4; ++ks) {
        const half4 av = *(const half4*)(pkS + (size_t)((mt * 4 + ks) * 64 + lane) * 4);
        acc = __builtin_amdgcn_mfma_f32_16x16x16f16(av, bf4[ks], acc, 0, 0, 0);
      }
      const int o0 = mt * 16 + quad * 4;
#pragma unroll
      for (int r = 0; r < 4; ++r) {
        const float z = acc[r];
        s += (z / (1.f + __expf(-z))) * w4[o0 + r];
      }
    }
    s += __shfl_xor(s, 16, 64);
    s += __shfl_xor(s, 32, 64);
    if (quad == 0) out[(size_t)(b0 + col) * OUT_COLS] = s * 0.125f;
  } else {
    const int t0 = (wv == 1) ? 0 : (wv == 2) ? 6 : 11;
    const int tn = (wv == 1) ? 6 : 5;
    for (int t = 0; t < tn; ++t) {
      const int mt = t0 + t;
      f32x4 acc = {0.f, 0.f, 0.f, 0.f};
#pragma unroll
      for (int ks = 0; ks < 4; ++ks) {
        const half4 av = *(const half4*)(pkG + (size_t)((mt * 4 + ks) * 64 + lane) * 4);
        acc = __builtin_amdgcn_mfma_f32_16x16x16f16(av, bf4[ks], acc, 0, 0, 0);
      }
      const int o0 = mt * 16 + quad * 4;
      half4 g;
#pragma unroll
      for (int r = 0; r < 4; ++r) g[r] = (_Float16)(1.f / (1.f + __expf(-acc[r])));
      *(half4*)(G3v + col * GP + o0) = g;
    }
  }
}

// ---------------------------------------------------------------------------
// Main kernel.
// ---------------------------------------------------------------------------
__global__ __launch_bounds__(256, 2) void fused_decoder(
    const float* __restrict__ vraw, const float* __restrict__ w4,
    const _Float16* __restrict__ pk, float* __restrict__ out)
{
  __shared__ __align__(16) _Float16 smem[SMEM_ELTS];
  _Float16* G1  = smem + OFF_G1;
  _Float16* G2  = smem + OFF_G2;
  _Float16* G3  = smem + OFF_G3;
  _Float16* Hs1 = smem + OFF_HS1;
  _Float16* Hs2 = smem + OFF_HS2;
  const int wv = threadIdx.x >> 6;
  float* scrw = (float*)(smem + OFF_SCR) + wv * SCRW_F;
  const int b0 = blockIdx.x * B_ROWS;

  half8 sf[8];
  load_scal_frags(vraw, b0, sf);
  scal_L1(sf, pk, Hs1, G1);
  __syncthreads();
  scal_mid(Hs1, pk + P2BASE, pk + P2BASE + 4096, Hs2, G2);
  __syncthreads();
  scal_last(Hs2, pk + P3BASE, pk + P3BASE + 4096, G3, w4, out, b0);
  __syncthreads();

  // phase 2: cost-balanced static wave assignment (no barriers).
  if (wv == 0) {
    run_chain<2, 0, 5>(vraw, pk, G1, G2, G3, w4, out, b0);
    run_chain_staged<3, 0, 4>(vraw, pk, G1, G2, G3, w4, out, b0, scrw);
  } else if (wv == 1) {
    run_chain<1, 0, 3>(vraw, pk, G1, G2, G3, w4, out, b0);
    run_chain_staged<3, 4, 3>(vraw, pk, G1, G2, G3, w4, out, b0, scrw);
    run_chain_staged<4, 0, 5>(vraw, pk, G1, G2, G3, w4, out, b0, scrw);
  } else if (wv == 2) {
    run_chain_staged<6, 0, 13>(vraw, pk, G1, G2, G3, w4, out, b0, scrw);
    run_chain_staged<4, 5, 1>(vraw, pk, G1, G2, G3, w4, out, b0, scrw);
  } else {
    run_chain_staged<5, 0, 11>(vraw, pk, G1, G2, G3, w4, out, b0, scrw);
    run_chain_staged<4, 6, 3>(vraw, pk, G1, G2, G3, w4, out, b0, scrw);
  }
}

extern "C" void kernel_launch(void* const* d_in, const int* in_sizes, int n_in,
                              void* d_out, int out_size, void* d_ws, size_t ws_size,
                              hipStream_t stream)
{
  (void)in_sizes; (void)n_in; (void)out_size; (void)ws_size;
  const float* vraw = (const float*)d_in[0];
  const float* w1   = (const float*)d_in[1];
  const float* w2   = (const float*)d_in[2];
  const float* w3   = (const float*)d_in[3];
  const float* w4   = (const float*)d_in[4];
  float* out = (float*)d_out;
  _Float16* packed = (_Float16*)d_ws;   // 172032 elems = 344064 B

  prep_weights<<<84, 256, 0, stream>>>(w1, w2, w3, packed);
  fused_decoder<<<16384 / B_ROWS, 256, 0, stream>>>(vraw, w4, packed, out);
}

// Round 17
// 372.600 us; speedup vs baseline: 1.0965x; 1.0143x over previous
//
#include <hip/hip_runtime.h>
#include <cstddef>

// ---------------------------------------------------------------------------
// Fused equivariant decoder, MI355X (gfx950) — round 12 (2nd resubmit; R15/
// R16 broker timeouts left it unmeasured).
// R11 measured (R14 bench): dur 408.6 -> 377.9us; decoder dropped OUT of the
//   top-5 (<147us vs 162-180 before) — first decoder movement in 7 measured
//   rounds. Address/segment-throughput theory partially confirmed.
// R12: complete the mechanism.
//   (1) L1/L2 chains also LDS-staged (K1=128 rows; 6/4-row windows, fits
//       2592-float wave scratch). Remaining ~256 scattered gathers coalesced.
//   (2) Scratch pitch padded NW->NW+4 (NWP): old pitch %32==0 aliased rows
//       onto the same LDS banks for EVERY L; pad spreads banks by 4/row.
// LDS 71.4KB, 2 blocks/CU, launch_bounds (256,2). Weights pre-packed in d_ws.
// ---------------------------------------------------------------------------

typedef _Float16 half8 __attribute__((ext_vector_type(8)));
typedef _Float16 half4 __attribute__((ext_vector_type(4)));
typedef float    f32x4 __attribute__((ext_vector_type(4)));
typedef float    fvec4 __attribute__((ext_vector_type(4)));

#define B_ROWS   16
#define IN_DIM   3840
#define OUT_COLS 49
#define GP  264           // gate row pitch (256 used)
#define HSP 72            // scalar-hidden row pitch (64 used)

// LDS map (elements of _Float16); bases all 16B-aligned.
#define OFF_G1  0         // 16*264 = 4224
#define OFF_G2  4224
#define OFF_G3  8448
#define OFF_HS1 12672     // 16*72 = 1152
#define OFF_HS2 13824
#define OFF_SCR 14976     // byte 29952; + wave*2592 floats (10368 B)
#define SCRW_F  2592      // floats per wave (max need 2576: L2 4x644)
#define SMEM_ELTS 35712   // 14976 + 4*2592*2 halves = 71424 B

#define P2BASE 106496
#define P3BASE 139264

// ---------------------------------------------------------------------------
// Weight prep (unchanged from R10/R11).
// bi 0..7  (w1, 16x16x32): frag f=(mt*KF+kf)*64+lane holds half8:
//   W[i][o]*scale, i=kf*32+(lane>>4)*8+j, o=mt*16+(lane&15).
// bi 8..23 (w2/w3, 16x16x16): frag f=mt*(K/16)+ks, lane holds half4:
//   W[i][o]*scale, i=ks*16+(lane>>4)*4+j, o=mt*16+(lane&15).
// ---------------------------------------------------------------------------
__global__ __launch_bounds__(256) void prep_weights(
    const float* __restrict__ w1, const float* __restrict__ w2,
    const float* __restrict__ w3, _Float16* __restrict__ packed)
{
  static const int K_[24]    = {256,256,128,128,64,64,64,64,  64,64,64,64,32,32,32,32,
                                64,64,64,64,32,32,32,32};
  static const int N_[24]    = {64,256,64,64,32,32,32,32,  64,256,64,64,32,32,32,32,
                                64,256,64,64,32,32,32,32};
  static const int woff_[24] = {0,16384,81920,90112,98304,100352,102400,104448,
                                0,4096,20480,24576,28672,29696,30720,31744,
                                0,4096,20480,24576,28672,29696,30720,31744};
  static const int poff_[24] = {0,16384,81920,90112,98304,100352,102400,104448,
                                106496,110592,126976,131072,135168,136192,137216,138240,
                                139264,143360,159744,163840,167936,168960,169984,171008};
  const int g = blockIdx.x * 256 + threadIdx.x;   // 0 .. 21503
  int bi = 0;
#pragma unroll
  for (int i = 1; i < 24; ++i) if (g * 8 >= poff_[i]) bi = i;
  const float* w = (bi < 8) ? w1 : ((bi < 16) ? w2 : w3);
  const int rel8 = g - poff_[bi] / 8;
  const int K = K_[bi], N = N_[bi];
  const float scale = 1.0f / sqrtf((float)K);
  half8 vv;
  if (bi < 8) {
    const int lane = rel8 & 63;
    const int fi   = rel8 >> 6;
    const int KF = K >> 5;
    const int kf = fi % KF;
    const int mt = fi / KF;
    const int k0 = kf * 32 + (lane >> 4) * 8;
    const int o  = mt * 16 + (lane & 15);
#pragma unroll
    for (int j = 0; j < 8; ++j)
      vv[j] = (_Float16)(w[woff_[bi] + (size_t)(k0 + j) * N + o] * scale);
  } else {
    const int f  = rel8 >> 5;
    const int lp = (rel8 & 31) << 1;
    const int KF16 = K >> 4;
    const int ks = f % KF16;
    const int mt = f / KF16;
#pragma unroll
    for (int t = 0; t < 2; ++t) {
      const int l  = lp + t;
      const int i0 = ks * 16 + (l >> 4) * 4;
      const int o  = mt * 16 + (l & 15);
#pragma unroll
      for (int j = 0; j < 4; ++j)
        vv[t * 4 + j] = (_Float16)(w[woff_[bi] + (size_t)(i0 + j) * N + o] * scale);
    }
  }
  *(half8*)(packed + (size_t)g * 8) = vv;
}

// ---------------------------------------------------------------------------
// Per-chain compile-time parameters.
// ---------------------------------------------------------------------------
template<int L> struct CP {
  static constexpr int TWOL1 = 2 * L + 1;
  static constexpr int K1  = (L <= 2) ? 128 : 64;
  static constexpr int N1  = (L <= 2) ? 64  : 32;
  static constexpr int KF1 = K1 / 32;
  static constexpr int MT  = N1 / 16;
  static constexpr int INOFF = (L==1)?256:(L==2)?640:(L==3)?1280:(L==4)?1728:(L==5)?2304:3008;
  static constexpr int P1    = (L==1)?81920:(L==2)?90112:(L==3)?98304:(L==4)?100352:(L==5)?102400:104448;
  static constexpr int P2R   = (L==1)?20480:(L==2)?24576:(L==3)?28672:(L==4)?29696:(L==5)?30720:31744;
  static constexpr int GO    = (L==1)?0:(L==2)?64:(L==3)?128:(L==4)?160:(L==5)?192:224;
  static constexpr int W4O   = (L==1)?64:(L==2)?128:(L==3)?192:(L==4)?224:(L==5)?256:288;
  static constexpr float SCALE = (N1 == 64) ? 0.125f : 0.17677669529663687f;
};

// ---------------------------------------------------------------------------
// Coalesced LDS staging (ALL chains).
// Unit ct needs rows blo..bhi of the chain's contiguous TWOL1*K1-dword row
// blocks. stage_issue: coalesced dwordx4 -> regs (clamped tail reloads last
// chunk). stage_write: ds_write_b128 to wave-private scratch at PADDED pitch
// NWP (breaks %32 bank aliasing). read_frags: strided ds_read of the MFMA
// B-fragment, converted to half.
// ---------------------------------------------------------------------------
template<int L> struct SG {
  static constexpr int NW   = CP<L>::TWOL1 * CP<L>::K1; // dwords per row block
  static constexpr int NWP  = NW + 4;                   // padded LDS pitch
  static constexpr int NW4  = NW / 4;                   // dwordx4 chunks/row
  static constexpr int ROWS = (L == 1) ? 6 : (L <= 3) ? 4 : 3;  // max rows/unit
  static constexpr int MAXIT = (NW4 * ROWS + 63) / 64;
};
// Scratch bound: max_L ROWS*NWP = L2: 4*644 = 2576 <= SCRW_F.

template<int L>
__device__ __forceinline__ void stage_issue(const float* __restrict__ vraw,
    int b0, int ct, fvec4 (&rv)[SG<L>::MAXIT])
{
  using P = CP<L>;
  const int lane = threadIdx.x & 63;
  const int blo = (ct * 16) / P::TWOL1;
  const int bhi = (ct * 16 + 15) / P::TWOL1;
  const int chunks = SG<L>::NW4 * (bhi - blo + 1);
  const float* base = vraw + (size_t)(b0 + blo) * IN_DIM + P::INOFF;
#pragma unroll
  for (int it = 0; it < SG<L>::MAXIT; ++it) {
    int t = it * 64 + lane;
    t = (t < chunks) ? t : (chunks - 1);          // clamp: redundant reload, safe
    const int r = t / SG<L>::NW4;
    const int o = t - r * SG<L>::NW4;
    rv[it] = *(const fvec4*)(base + (size_t)r * IN_DIM + o * 4);
  }
}

template<int L>
__device__ __forceinline__ void stage_write(const fvec4 (&rv)[SG<L>::MAXIT],
    float* scr, int ct)
{
  using P = CP<L>;
  const int lane = threadIdx.x & 63;
  const int blo = (ct * 16) / P::TWOL1;
  const int bhi = (ct * 16 + 15) / P::TWOL1;
  const int chunks = SG<L>::NW4 * (bhi - blo + 1);
#pragma unroll
  for (int it = 0; it < SG<L>::MAXIT; ++it) {
    int t = it * 64 + lane;
    t = (t < chunks) ? t : (chunks - 1);          // duplicate writes of same data
    const int r = t / SG<L>::NW4;
    const int o = t - r * SG<L>::NW4;
    *(fvec4*)(scr + r * SG<L>::NWP + o * 4) = rv[it];
  }
}

template<int L>
__device__ __forceinline__ void read_frags(const float* scr, int ct,
                                           half8 (&bf)[CP<L>::KF1])
{
  using P = CP<L>;
  const int lane = threadIdx.x & 63;
  const int col  = lane & 15;
  const int quad = lane >> 4;
  const int c = ct * 16 + col;
  const int blo = (ct * 16) / P::TWOL1;
  const int b = c / P::TWOL1;
  const int m = c - b * P::TWOL1;
  const float* base = scr + (b - blo) * SG<L>::NWP + m + quad * 8 * P::TWOL1;
#pragma unroll
  for (int kf = 0; kf < P::KF1; ++kf)
#pragma unroll
    for (int j = 0; j < 8; ++j)
      bf[kf][j] = (_Float16)base[(kf * 32 + j) * P::TWOL1];
}

// ---------------------------------------------------------------------------
// Unit computes (unchanged).
// ---------------------------------------------------------------------------
template<int L>
__device__ __forceinline__ void unit_compute(
    const half8 (&bf)[CP<L>::KF1], const _Float16* __restrict__ pk,
    const _Float16* G1, const _Float16* G2, const _Float16* G3,
    const float* __restrict__ w4, float* __restrict__ out, int b0, int ct)
{
  using P = CP<L>;
  const int lane = threadIdx.x & 63;
  const int col  = lane & 15;
  const int quad = lane >> 4;
  const int c = ct * 16 + col;
  const int b = c / P::TWOL1;
  const int m = c - b * P::TWOL1;

  half4 ph1[P::MT];
#pragma unroll
  for (int mt = 0; mt < P::MT; ++mt) {
    f32x4 acc = {0.f, 0.f, 0.f, 0.f};
#pragma unroll
    for (int kf = 0; kf < P::KF1; ++kf) {
      const half8 av = *(const half8*)(pk + P::P1 + (size_t)((mt * P::KF1 + kf) * 64 + lane) * 8);
      acc = __builtin_amdgcn_mfma_f32_16x16x32_f16(av, bf[kf], acc, 0, 0, 0);
    }
    const int o0 = mt * 16 + quad * 4;
    const half4 g4 = *(const half4*)(G1 + b * GP + P::GO + o0);
    half4 h;
#pragma unroll
    for (int r = 0; r < 4; ++r) h[r] = (_Float16)(acc[r] * (float)g4[r]);
    ph1[mt] = h;
  }

  half4 ph2[P::MT];
#pragma unroll
  for (int mt = 0; mt < P::MT; ++mt) {
    f32x4 acc = {0.f, 0.f, 0.f, 0.f};
#pragma unroll
    for (int ks = 0; ks < P::MT; ++ks) {
      const half4 av = *(const half4*)(pk + P2BASE + P::P2R + (size_t)((mt * P::MT + ks) * 64 + lane) * 4);
      acc = __builtin_amdgcn_mfma_f32_16x16x16f16(av, ph1[ks], acc, 0, 0, 0);
    }
    const int o0 = mt * 16 + quad * 4;
    const half4 g4 = *(const half4*)(G2 + b * GP + P::GO + o0);
    half4 h;
#pragma unroll
    for (int r = 0; r < 4; ++r) h[r] = (_Float16)(acc[r] * (float)g4[r]);
    ph2[mt] = h;
  }

  float s = 0.f;
#pragma unroll
  for (int mt = 0; mt < P::MT; ++mt) {
    f32x4 acc = {0.f, 0.f, 0.f, 0.f};
#pragma unroll
    for (int ks = 0; ks < P::MT; ++ks) {
      const half4 av = *(const half4*)(pk + P3BASE + P::P2R + (size_t)((mt * P::MT + ks) * 64 + lane) * 4);
      acc = __builtin_amdgcn_mfma_f32_16x16x16f16(av, ph2[ks], acc, 0, 0, 0);
    }
    const int o0 = mt * 16 + quad * 4;
    const half4 g4 = *(const half4*)(G3 + b * GP + P::GO + o0);
#pragma unroll
    for (int r = 0; r < 4; ++r)
      s += acc[r] * (float)g4[r] * w4[P::W4O + o0 + r];
  }
  s += __shfl_xor(s, 16, 64);
  s += __shfl_xor(s, 32, 64);
  if (quad == 0)
    out[(size_t)(b0 + b) * OUT_COLS + L * L + m] = s * P::SCALE;
}

template<int L>
__device__ __forceinline__ void unit_compute_reg(
    const half8 (&bf)[CP<L>::KF1],
    const half8 (&aw1)[CP<L>::MT * CP<L>::KF1],
    const half4 (&aw2)[CP<L>::MT * CP<L>::MT],
    const half4 (&aw3)[CP<L>::MT * CP<L>::MT],
    const _Float16* G1, const _Float16* G2, const _Float16* G3,
    const float* __restrict__ w4, float* __restrict__ out, int b0, int ct)
{
  using P = CP<L>;
  const int lane = threadIdx.x & 63;
  const int col  = lane & 15;
  const int quad = lane >> 4;
  const int c = ct * 16 + col;
  const int b = c / P::TWOL1;
  const int m = c - b * P::TWOL1;

  half4 ph1[P::MT];
#pragma unroll
  for (int mt = 0; mt < P::MT; ++mt) {
    f32x4 acc = {0.f, 0.f, 0.f, 0.f};
#pragma unroll
    for (int kf = 0; kf < P::KF1; ++kf)
      acc = __builtin_amdgcn_mfma_f32_16x16x32_f16(aw1[mt * P::KF1 + kf], bf[kf], acc, 0, 0, 0);
    const int o0 = mt * 16 + quad * 4;
    const half4 g4 = *(const half4*)(G1 + b * GP + P::GO + o0);
    half4 h;
#pragma unroll
    for (int r = 0; r < 4; ++r) h[r] = (_Float16)(acc[r] * (float)g4[r]);
    ph1[mt] = h;
  }

  half4 ph2[P::MT];
#pragma unroll
  for (int mt = 0; mt < P::MT; ++mt) {
    f32x4 acc = {0.f, 0.f, 0.f, 0.f};
#pragma unroll
    for (int ks = 0; ks < P::MT; ++ks)
      acc = __builtin_amdgcn_mfma_f32_16x16x16f16(aw2[mt * P::MT + ks], ph1[ks], acc, 0, 0, 0);
    const int o0 = mt * 16 + quad * 4;
    const half4 g4 = *(const half4*)(G2 + b * GP + P::GO + o0);
    half4 h;
#pragma unroll
    for (int r = 0; r < 4; ++r) h[r] = (_Float16)(acc[r] * (float)g4[r]);
    ph2[mt] = h;
  }

  float s = 0.f;
#pragma unroll
  for (int mt = 0; mt < P::MT; ++mt) {
    f32x4 acc = {0.f, 0.f, 0.f, 0.f};
#pragma unroll
    for (int ks = 0; ks < P::MT; ++ks)
      acc = __builtin_amdgcn_mfma_f32_16x16x16f16(aw3[mt * P::MT + ks], ph2[ks], acc, 0, 0, 0);
    const int o0 = mt * 16 + quad * 4;
    const half4 g4 = *(const half4*)(G3 + b * GP + P::GO + o0);
#pragma unroll
    for (int r = 0; r < 4; ++r)
      s += acc[r] * (float)g4[r] * w4[P::W4O + o0 + r];
  }
  s += __shfl_xor(s, 16, 64);
  s += __shfl_xor(s, 32, 64);
  if (quad == 0)
    out[(size_t)(b0 + b) * OUT_COLS + L * L + m] = s * P::SCALE;
}

// ---------------------------------------------------------------------------
// Chain runner: ALL chains LDS-staged, T14 split (issue early / write late).
// L>=3 additionally hoists weights to registers (24 VGPR). Wave-private scr,
// no fences (in-order DS per wave: reads of unit u are issued before writes
// of unit u+1 that overwrite the same region).
// ---------------------------------------------------------------------------
template<int L, int CT0, int NCT>
__device__ __forceinline__ void run_chain_staged(
    const float* __restrict__ vraw, const _Float16* __restrict__ pk,
    const _Float16* G1, const _Float16* G2, const _Float16* G3,
    const float* __restrict__ w4, float* __restrict__ out, int b0, float* scr)
{
  using P = CP<L>;
  fvec4 rv[SG<L>::MAXIT];
  stage_issue<L>(vraw, b0, CT0, rv);
  if constexpr (L >= 3) {
    const int lane = threadIdx.x & 63;
    half8 aw1[P::MT * P::KF1];
    half4 aw2[P::MT * P::MT];
    half4 aw3[P::MT * P::MT];
#pragma unroll
    for (int f = 0; f < P::MT * P::KF1; ++f)
      aw1[f] = *(const half8*)(pk + P::P1 + (size_t)(f * 64 + lane) * 8);
#pragma unroll
    for (int f = 0; f < P::MT * P::MT; ++f) {
      aw2[f] = *(const half4*)(pk + P2BASE + P::P2R + (size_t)(f * 64 + lane) * 4);
      aw3[f] = *(const half4*)(pk + P3BASE + P::P2R + (size_t)(f * 64 + lane) * 4);
    }
    stage_write<L>(rv, scr, CT0);
#pragma unroll 1
    for (int u = 0; u < NCT; ++u) {
      half8 bf[P::KF1];
      read_frags<L>(scr, CT0 + u, bf);
      if (u + 1 < NCT) stage_issue<L>(vraw, b0, CT0 + u + 1, rv);
      unit_compute_reg<L>(bf, aw1, aw2, aw3, G1, G2, G3, w4, out, b0, CT0 + u);
      if (u + 1 < NCT) stage_write<L>(rv, scr, CT0 + u + 1);
    }
  } else {
    stage_write<L>(rv, scr, CT0);
#pragma unroll 1
    for (int u = 0; u < NCT; ++u) {
      half8 bf[P::KF1];
      read_frags<L>(scr, CT0 + u, bf);
      if (u + 1 < NCT) stage_issue<L>(vraw, b0, CT0 + u + 1, rv);
      unit_compute<L>(bf, pk, G1, G2, G3, w4, out, b0, CT0 + u);
      if (u + 1 < NCT) stage_write<L>(rv, scr, CT0 + u + 1);
    }
  }
}

// ---------------------------------------------------------------------------
// Scalar (l=0) chain (unchanged).
// ---------------------------------------------------------------------------
__device__ __forceinline__ void load_scal_frags(const float* __restrict__ vraw,
                                                int b0, half8 (&sf)[8])
{
  const int lane = threadIdx.x & 63;
  const int col  = lane & 15;
  const int quad = lane >> 4;
  const float* base = vraw + (size_t)(b0 + col) * IN_DIM + quad * 8;
#pragma unroll
  for (int kf = 0; kf < 8; ++kf) {
    const fvec4 a = *(const fvec4*)(base + kf * 32);
    const fvec4 b2 = *(const fvec4*)(base + kf * 32 + 4);
#pragma unroll
    for (int j = 0; j < 4; ++j) { sf[kf][j] = (_Float16)a[j]; sf[kf][4 + j] = (_Float16)b2[j]; }
  }
}

__device__ __forceinline__ void scal_L1(const half8 (&sf)[8],
    const _Float16* __restrict__ pk, _Float16* Hs1, _Float16* G1v)
{
  const int lane = threadIdx.x & 63;
  const int wv   = threadIdx.x >> 6;
  const int col  = lane & 15;
  const int quad = lane >> 4;
  {
    f32x4 acc = {0.f, 0.f, 0.f, 0.f};
#pragma unroll
    for (int kf = 0; kf < 8; ++kf) {
      const half8 av = *(const half8*)(pk + (size_t)((wv * 8 + kf) * 64 + lane) * 8);
      acc = __builtin_amdgcn_mfma_f32_16x16x32_f16(av, sf[kf], acc, 0, 0, 0);
    }
    const int o0 = wv * 16 + quad * 4;
    half4 h;
#pragma unroll
    for (int r = 0; r < 4; ++r) { const float z = acc[r]; h[r] = (_Float16)(z / (1.f + __expf(-z))); }
    *(half4*)(Hs1 + col * HSP + o0) = h;
  }
#pragma unroll
  for (int t = 0; t < 4; ++t) {
    const int mt = wv * 4 + t;
    f32x4 acc = {0.f, 0.f, 0.f, 0.f};
#pragma unroll
    for (int kf = 0; kf < 8; ++kf) {
      const half8 av = *(const half8*)(pk + 16384 + (size_t)((mt * 8 + kf) * 64 + lane) * 8);
      acc = __builtin_amdgcn_mfma_f32_16x16x32_f16(av, sf[kf], acc, 0, 0, 0);
    }
    const int o0 = mt * 16 + quad * 4;
    half4 g;
#pragma unroll
    for (int r = 0; r < 4; ++r) g[r] = (_Float16)(1.f / (1.f + __expf(-acc[r])));
    *(half4*)(G1v + col * GP + o0) = g;
  }
}

__device__ __forceinline__ void scal_mid(const _Float16* HsIn,
    const _Float16* __restrict__ pkS, const _Float16* __restrict__ pkG,
    _Float16* HsOut, _Float16* Gv)
{
  const int lane = threadIdx.x & 63;
  const int wv   = threadIdx.x >> 6;
  const int col  = lane & 15;
  const int quad = lane >> 4;
  half4 bf4[4];
#pragma unroll
  for (int ks = 0; ks < 4; ++ks)
    bf4[ks] = *(const half4*)(HsIn + col * HSP + ks * 16 + quad * 4);
  {
    f32x4 acc = {0.f, 0.f, 0.f, 0.f};
#pragma unroll
    for (int ks = 0; ks < 4; ++ks) {
      const half4 av = *(const half4*)(pkS + (size_t)((wv * 4 + ks) * 64 + lane) * 4);
      acc = __builtin_amdgcn_mfma_f32_16x16x16f16(av, bf4[ks], acc, 0, 0, 0);
    }
    const int o0 = wv * 16 + quad * 4;
    half4 h;
#pragma unroll
    for (int r = 0; r < 4; ++r) { const float z = acc[r]; h[r] = (_Float16)(z / (1.f + __expf(-z))); }
    *(half4*)(HsOut + col * HSP + o0) = h;
  }
#pragma unroll
  for (int t = 0; t < 4; ++t) {
    const int mt = wv * 4 + t;
    f32x4 acc = {0.f, 0.f, 0.f, 0.f};
#pragma unroll
    for (int ks = 0; ks < 4; ++ks) {
      const half4 av = *(const half4*)(pkG + (size_t)((mt * 4 + ks) * 64 + lane) * 4);
      acc = __builtin_amdgcn_mfma_f32_16x16x16f16(av, bf4[ks], acc, 0, 0, 0);
    }
    const int o0 = mt * 16 + quad * 4;
    half4 g;
#pragma unroll
    for (int r = 0; r < 4; ++r) g[r] = (_Float16)(1.f / (1.f + __expf(-acc[r])));
    *(half4*)(Gv + col * GP + o0) = g;
  }
}

__device__ __forceinline__ void scal_last(const _Float16* Hs2,
    const _Float16* __restrict__ pkS, const _Float16* __restrict__ pkG,
    _Float16* G3v, const float* __restrict__ w4, float* __restrict__ out, int b0)
{
  const int lane = threadIdx.x & 63;
  const int wv   = threadIdx.x >> 6;
  const int col  = lane & 15;
  const int quad = lane >> 4;
  half4 bf4[4];
#pragma unroll
  for (int ks = 0; ks < 4; ++ks)
    bf4[ks] = *(const half4*)(Hs2 + col * HSP + ks * 16 + quad * 4);
  if (wv == 0) {
    float s = 0.f;
#pragma unroll
    for (int mt = 0; mt < 4; ++mt) {
      f32x4 acc = {0.f, 0.f, 0.f, 0.f};
#pragma unroll
      for (int ks = 0; ks < 4; ++ks) {
        const half4 av = *(const half4*)(pkS + (size_t)((mt * 4 + ks) * 64 + lane) * 4);
        acc = __builtin_amdgcn_mfma_f32_16x16x16f16(av, bf4[ks], acc, 0, 0, 0);
      }
      const int o0 = mt * 16 + quad * 4;
#pragma unroll
      for (int r = 0; r < 4; ++r) {
        const float z = acc[r];
        s += (z / (1.f + __expf(-z))) * w4[o0 + r];
      }
    }
    s += __shfl_xor(s, 16, 64);
    s += __shfl_xor(s, 32, 64);
    if (quad == 0) out[(size_t)(b0 + col) * OUT_COLS] = s * 0.125f;
  } else {
    const int t0 = (wv == 1) ? 0 : (wv == 2) ? 6 : 11;
    const int tn = (wv == 1) ? 6 : 5;
    for (int t = 0; t < tn; ++t) {
      const int mt = t0 + t;
      f32x4 acc = {0.f, 0.f, 0.f, 0.f};
#pragma unroll
      for (int ks = 0; ks < 4; ++ks) {
        const half4 av = *(const half4*)(pkG + (size_t)((mt * 4 + ks) * 64 + lane) * 4);
        acc = __builtin_amdgcn_mfma_f32_16x16x16f16(av, bf4[ks], acc, 0, 0, 0);
      }
      const int o0 = mt * 16 + quad * 4;
      half4 g;
#pragma unroll
      for (int r = 0; r < 4; ++r) g[r] = (_Float16)(1.f / (1.f + __expf(-acc[r])));
      *(half4*)(G3v + col * GP + o0) = g;
    }
  }
}

// ---------------------------------------------------------------------------
// Main kernel.
// ---------------------------------------------------------------------------
__global__ __launch_bounds__(256, 2) void fused_decoder(
    const float* __restrict__ vraw, const float* __restrict__ w4,
    const _Float16* __restrict__ pk, float* __restrict__ out)
{
  __shared__ __align__(16) _Float16 smem[SMEM_ELTS];
  _Float16* G1  = smem + OFF_G1;
  _Float16* G2  = smem + OFF_G2;
  _Float16* G3  = smem + OFF_G3;
  _Float16* Hs1 = smem + OFF_HS1;
  _Float16* Hs2 = smem + OFF_HS2;
  const int wv = threadIdx.x >> 6;
  float* scrw = (float*)(smem + OFF_SCR) + wv * SCRW_F;
  const int b0 = blockIdx.x * B_ROWS;

  half8 sf[8];
  load_scal_frags(vraw, b0, sf);
  scal_L1(sf, pk, Hs1, G1);
  __syncthreads();
  scal_mid(Hs1, pk + P2BASE, pk + P2BASE + 4096, Hs2, G2);
  __syncthreads();
  scal_last(Hs2, pk + P3BASE, pk + P3BASE + 4096, G3, w4, out, b0);
  __syncthreads();

  // phase 2: cost-balanced static wave assignment (no barriers).
  if (wv == 0) {
    run_chain_staged<2, 0, 5>(vraw, pk, G1, G2, G3, w4, out, b0, scrw);
    run_chain_staged<3, 0, 4>(vraw, pk, G1, G2, G3, w4, out, b0, scrw);
  } else if (wv == 1) {
    run_chain_staged<1, 0, 3>(vraw, pk, G1, G2, G3, w4, out, b0, scrw);
    run_chain_staged<3, 4, 3>(vraw, pk, G1, G2, G3, w4, out, b0, scrw);
    run_chain_staged<4, 0, 5>(vraw, pk, G1, G2, G3, w4, out, b0, scrw);
  } else if (wv == 2) {
    run_chain_staged<6, 0, 13>(vraw, pk, G1, G2, G3, w4, out, b0, scrw);
    run_chain_staged<4, 5, 1>(vraw, pk, G1, G2, G3, w4, out, b0, scrw);
  } else {
    run_chain_staged<5, 0, 11>(vraw, pk, G1, G2, G3, w4, out, b0, scrw);
    run_chain_staged<4, 6, 3>(vraw, pk, G1, G2, G3, w4, out, b0, scrw);
  }
}

extern "C" void kernel_launch(void* const* d_in, const int* in_sizes, int n_in,
                              void* d_out, int out_size, void* d_ws, size_t ws_size,
                              hipStream_t stream)
{
  (void)in_sizes; (void)n_in; (void)out_size; (void)ws_size;
  const float* vraw = (const float*)d_in[0];
  const float* w1   = (const float*)d_in[1];
  const float* w2   = (const float*)d_in[2];
  const float* w3   = (const float*)d_in[3];
  const float* w4   = (const float*)d_in[4];
  float* out = (float*)d_out;
  _Float16* packed = (_Float16*)d_ws;   // 172032 elems = 344064 B

  prep_weights<<<84, 256, 0, stream>>>(w1, w2, w3, packed);
  fused_decoder<<<16384 / B_ROWS, 256, 0, stream>>>(vraw, w4, packed, out);
}